// Round 6
// baseline (150.059 us; speedup 1.0000x reference)
//
#include <hip/hip_runtime.h>
#include <cstdint>

// =====================================================================
// MultiHeadAttention_84576495993495  (round 13)
//
// Algebraic collapse: einsum('bhqk,bhvo->bhvo', attn, v) sums attn over
// BOTH q and k; softmax rows sum to 1 -> factor is exactly S=2048.
//   final = x @ (2048*Wp@Wv)^T + (2048*Wp@bv + bp)
// Wq/bq/Wk/bk unused.
//
// R13 theory: R12 (2x waves/SIMD) moved total only -1.4us => GEMM
// scheduling is no longer the dominant term; kernel-side total is
// ~45-60us and the rest is harness-fixed (256MB fills ~42us each in
// every rocprof top-5). Attack kernel-side WORK, not schedule:
//   - gemm0: fuse x f32->bf16 into A-staging (reg-stage: dwordx4 f32
//     -> cvt -> swizzled ds_write_b128; issue loads early, write after
//     MFMA = T14 split). Deletes xb round-trip: x traffic 64->32 MB.
//     B-side stays global_load_lds (inverse-perm source, unchanged).
//   - prep slimmed to 2304 blocks (Wp conv / Wv transpose / cv fold).
//   - gemm1 unchanged from R12 (glds both operands, 256 blocks).
// Schedule = R10/R12 2-phase drain-after-MFMA (verified best).
// Decision rule: if total >=136us, measured floor = harness overhead.
// =====================================================================

typedef unsigned short u16;
typedef __bf16 bf16x8 __attribute__((ext_vector_type(8)));
typedef float f32x4 __attribute__((ext_vector_type(4)));

__device__ __forceinline__ u16 f2bf(float f) {
  // round-to-nearest-even f32 -> bf16 bits (finite inputs)
  unsigned int u = __float_as_uint(f);
  u += 0x7fffu + ((u >> 16) & 1u);
  return (u16)(u >> 16);
}

__device__ __forceinline__ bf16x8 cvt8(float4 a, float4 b) {
  bf16x8 r;
  r[0] = (__bf16)a.x; r[1] = (__bf16)a.y; r[2] = (__bf16)a.z; r[3] = (__bf16)a.w;
  r[4] = (__bf16)b.x; r[5] = (__bf16)b.y; r[6] = (__bf16)b.z; r[7] = (__bf16)b.w;
  return r;
}

// async global->LDS 16B copy; LDS dest = wave-uniform base + lane*16
__device__ __forceinline__ void load16(const void* g, void* l) {
  auto gp = (const __attribute__((address_space(1))) unsigned int*)(uintptr_t)g;
  auto lp = (__attribute__((address_space(3))) unsigned int*)(unsigned int)(uintptr_t)l;
  __builtin_amdgcn_global_load_lds(gp, lp, 16, 0, 0);
}

// ---------------------------------------------------------------------
// Slim prep. Block ranges:
//   [0,1024)     conv Wp  f32->bf16 (4 elem/thread)
//   [1024,2048)  transpose+conv Wv -> Wv^T bf16 (32x32 tiles)
//   [2048,2304)  cv[n] = 2048*dot(Wp[n,:],bv) + bp[n]
__global__ void k_prep(const float* __restrict__ Wv, const float* __restrict__ bv,
                       const float* __restrict__ Wp, const float* __restrict__ bp,
                       u16* __restrict__ wpb, u16* __restrict__ wvtb,
                       float* __restrict__ cv) {
  __shared__ float tile[32][33];
  const int b = blockIdx.x;
  const int tid = threadIdx.x;
  if (b < 1024) {  // conv Wp
    const long base = (long)b * 1024 + tid * 4;
    const float4 v = *(const float4*)(Wp + base);
    ushort4 o;
    o.x = f2bf(v.x); o.y = f2bf(v.y); o.z = f2bf(v.z); o.w = f2bf(v.w);
    *(ushort4*)(wpb + base) = o;
  } else if (b < 2048) {  // transpose Wv
    const int tb = b - 1024;
    const int bi = (tb & 31) * 32;   // output row block (i)
    const int bj = (tb >> 5) * 32;   // output col block (j) = src row block
    const int tx = tid & 31;
    const int ty = tid >> 5;  // 0..7
    for (int r = ty; r < 32; r += 8)
      tile[r][tx] = Wv[(long)(bj + r) * 1024 + bi + tx];
    __syncthreads();
    for (int r = ty; r < 32; r += 8)
      wvtb[(long)(bi + r) * 1024 + bj + tx] = f2bf(tile[tx][r]);
  } else {  // bias fold
    const int row = (b - 2048) * 4 + (tid >> 6);
    const int lane = tid & 63;
    const float* w = Wp + (long)row * 1024;
    float s = 0.f;
    for (int j = lane; j < 1024; j += 64) s += w[j] * bv[j];
    for (int off = 32; off; off >>= 1) s += __shfl_down(s, off, 64);
    if (lane == 0) cv[row] = 2048.f * s + bp[row];
  }
}

// ---------------------------------------------------------------------
// NT bf16 GEMM: Out[M,N] = A[M,K] @ B[N,K]^T  (+bias or *2048->bf16)
// R10 schedule (verified best): 2-phase dbuf, per iter
//   STAGE(t+1) -> ds_read(t) -> lgkmcnt(0) -> MFMA -> drain -> barrier.
// LDS contract: 64 u16/row, slot c of row r holds logical chunk
// c ^ (r&7); fragment ds_read_b128 aliases 2-way (free, m136).
// MODE 0: A is f32 (x) -- reg-staged with fused cvt (issue loads at
//         top of iter, cvt+swizzled ds_write_b128 after MFMA); B via
//         global_load_lds (inverse-perm source). BM=BN=128, 512 thr =
//         8 waves (2Mx4N, wave tile 64x32, acc 4x2), f32 out + bias,
//         XCD-grouped 512-block grid, 64 KB LDS.
// MODE 1: A,B bf16 via global_load_lds. BM=BN=64, 256 thr = 4 waves
//         (2x2, wave tile 32x32, acc 2x2), bf16 out * 2048, 256 blocks.
template <int MODE>
__global__ __launch_bounds__(MODE == 0 ? 512 : 256) void k_gemm(
    const void* __restrict__ Ain, const u16* __restrict__ B, void* __restrict__ OutV,
    const float* __restrict__ bias, int M, int N, int K) {
  constexpr int BM = (MODE == 0) ? 128 : 64;
  constexpr int BN = (MODE == 0) ? 128 : 64;
  constexpr int T  = (MODE == 0) ? 512 : 256;
  constexpr int WTM = (MODE == 0) ? 64 : 32;  // wave tile M
  constexpr int WTN = 32;                      // wave tile N
  constexpr int AccM = WTM / 16;               // 4 or 2
  constexpr int AccN = WTN / 16;               // 2

  __shared__ u16 As[2][BM * 64];
  __shared__ u16 Bs[2][BN * 64];

  const int tid = threadIdx.x;
  const int lane = tid & 63;
  const int wv = tid >> 6;
  const int waveM = (wv & 1) * WTM;
  const int waveN = (wv >> 1) * WTN;
  const int l15 = lane & 15;
  const int quad = lane >> 4;

  long bm, bn;
  if constexpr (MODE == 0) {
    // XCD grouping: xcd = id&7 owns 8 contiguous m-panels; a panel's 8
    // n-blocks are temporally adjacent on that XCD (B = 2 MB L2-fits).
    const int id = blockIdx.x;            // gridDim.x = (M/128)*(N/128)
    const int xcd = id & 7;
    const int j = id >> 3;
    const int nb = N >> 7;
    const int mPerXcd = M / 128 / 8;
    bm = (long)(xcd * mPerXcd + j / nb) * 128;
    bn = (long)(j % nb) * 128;
  } else {
    bm = (long)(blockIdx.x >> 4) * 64;
    bn = (long)(blockIdx.x & 15) * 64;
  }

  const int nT = K >> 6;  // # K-tiles (16 for K=1024)

  // ---- B staging via global_load_lds (both modes) ----
  // Thread t: row = t>>3, LDS slot = t&7, global chunk = (t&7)^(row&7).
  const int rl = tid >> 3;
  const int cs = (tid & 7) ^ (rl & 7);
  const u16* Bg0 = B + (bn + rl) * (long)K + cs * 8;
  constexpr int RPC = T / 8;  // rows per glds call (64 or 32)

  // ---- A staging ----
  const float* Afg = nullptr;  // MODE 0: f32 x
  const u16* Ag0 = nullptr;    // MODE 1: bf16
  int ar = 0, as0 = 0, as1 = 0;
  if constexpr (MODE == 0) {
    const float* Af = (const float*)Ain;
    ar = tid >> 2;                       // row 0..127
    const int ap = tid & 3;              // chunk-pair index
    Afg = Af + (bm + ar) * (long)K + ap * 16;
    as0 = ((2 * ap)     ^ (ar & 7)) * 8;  // u16 offset of swizzled slot
    as1 = ((2 * ap + 1) ^ (ar & 7)) * 8;
  } else {
    Ag0 = (const u16*)Ain + (bm + rl) * (long)K + cs * 8;
  }

  const f32x4 zero = {0.f, 0.f, 0.f, 0.f};
  f32x4 acc[AccM][AccN];
#pragma unroll
  for (int i = 0; i < AccM; ++i)
#pragma unroll
    for (int j = 0; j < AccN; ++j) acc[i][j] = zero;

  // Fragment read slots (swizzled): logical chunk kk*4+quad of row
  // (..+l15) sits at slot ^ (l15&7)  (base rows are multiples of 8).
  const int rq0 = quad ^ (l15 & 7);        // kk = 0
  const int rq1 = (4 + quad) ^ (l15 & 7);  // kk = 1

  // ---- prologue: stage tile 0, drain, barrier ----
  if constexpr (MODE == 0) {
    const float4 v0 = *(const float4*)(Afg + 0);
    const float4 v1 = *(const float4*)(Afg + 4);
    const float4 v2 = *(const float4*)(Afg + 8);
    const float4 v3 = *(const float4*)(Afg + 12);
    u16* Bd = &Bs[0][0] + tid * 8;
    load16(Bg0, Bd);
    load16(Bg0 + (long)RPC * K, Bd + RPC * 64);
    u16* Aw = &As[0][0] + ar * 64;
    *(bf16x8*)(Aw + as0) = cvt8(v0, v1);
    *(bf16x8*)(Aw + as1) = cvt8(v2, v3);
  } else {
    u16* Ad = &As[0][0] + tid * 8;
    u16* Bd = &Bs[0][0] + tid * 8;
    load16(Ag0, Ad);
    load16(Ag0 + (long)RPC * K, Ad + RPC * 64);
    load16(Bg0, Bd);
    load16(Bg0 + (long)RPC * K, Bd + RPC * 64);
  }
  asm volatile("s_waitcnt vmcnt(0) lgkmcnt(0)" ::: "memory");
  __builtin_amdgcn_s_barrier();

  int cur = 0;
  for (int t = 0; t < nT; ++t) {
    const bool more = (t + 1) < nT;
    const long k1 = (long)(t + 1) << 6;

    float4 v0, v1, v2, v3;
    if (more) {
      if constexpr (MODE == 0) {
        // issue A f32 loads to regs + B glds for tile t+1
        const float* ag = Afg + k1;
        v0 = *(const float4*)(ag + 0);
        v1 = *(const float4*)(ag + 4);
        v2 = *(const float4*)(ag + 8);
        v3 = *(const float4*)(ag + 12);
        u16* Bd = &Bs[cur ^ 1][0] + tid * 8;
        load16(Bg0 + k1, Bd);
        load16(Bg0 + k1 + (long)RPC * K, Bd + RPC * 64);
      } else {
        u16* Ad = &As[cur ^ 1][0] + tid * 8;
        u16* Bd = &Bs[cur ^ 1][0] + tid * 8;
        load16(Ag0 + k1, Ad);
        load16(Ag0 + k1 + (long)RPC * K, Ad + RPC * 64);
        load16(Bg0 + k1, Bd);
        load16(Bg0 + k1 + (long)RPC * K, Bd + RPC * 64);
      }
    }
    __builtin_amdgcn_sched_barrier(0);  // keep stage issue ahead of reads

    const u16* Asb = &As[cur][0];
    const u16* Bsb = &Bs[cur][0];
    bf16x8 af[2][AccM], bg[2][AccN];
#pragma unroll
    for (int i = 0; i < AccM; ++i) {
      const int ra = (waveM + i * 16 + l15) * 64;
      af[0][i] = *(const bf16x8*)(Asb + ra + rq0 * 8);
      af[1][i] = *(const bf16x8*)(Asb + ra + rq1 * 8);
    }
#pragma unroll
    for (int j = 0; j < AccN; ++j) {
      const int rb = (waveN + j * 16 + l15) * 64;
      bg[0][j] = *(const bf16x8*)(Bsb + rb + rq0 * 8);
      bg[1][j] = *(const bf16x8*)(Bsb + rb + rq1 * 8);
    }
    asm volatile("s_waitcnt lgkmcnt(0)" ::: "memory");
    __builtin_amdgcn_sched_barrier(0);  // rule #18: no MFMA hoist past wait

#pragma unroll
    for (int kk = 0; kk < 2; ++kk)
#pragma unroll
      for (int i = 0; i < AccM; ++i)
#pragma unroll
        for (int j = 0; j < AccN; ++j)
          acc[i][j] = __builtin_amdgcn_mfma_f32_16x16x32_bf16(af[kk][i], bg[kk][j],
                                                              acc[i][j], 0, 0, 0);

    if (more) {
      if constexpr (MODE == 0) {
        // write-late half of the A stage (T14): buffer cur^1 was last
        // read before the previous barrier -> WAR-safe.
        u16* Aw = &As[cur ^ 1][0] + ar * 64;
        *(bf16x8*)(Aw + as0) = cvt8(v0, v1);  // compiler waits A regs
        *(bf16x8*)(Aw + as1) = cvt8(v2, v3);
      }
      // drain B glds (+ make ds_writes visible), then join
      asm volatile("s_waitcnt vmcnt(0) lgkmcnt(0)" ::: "memory");
      __builtin_amdgcn_s_barrier();
      cur ^= 1;
    }
  }

  // epilogue: C/D layout col = lane&15, row = quad*4 + reg  [m89/m91]
#pragma unroll
  for (int i = 0; i < AccM; ++i) {
    const long gm = bm + waveM + i * 16 + quad * 4;
#pragma unroll
    for (int j = 0; j < AccN; ++j) {
      const long gn = bn + waveN + j * 16 + l15;
      if constexpr (MODE == 0) {
        float* outp = (float*)OutV;
        const float bb = bias[gn];
#pragma unroll
        for (int r = 0; r < 4; ++r)
          outp[(gm + r) * N + gn] = acc[i][j][r] + bb;
      } else {
        u16* outp = (u16*)OutV;
#pragma unroll
        for (int r = 0; r < 4; ++r)
          outp[(gm + r) * N + gn] = f2bf(acc[i][j][r] * 2048.f);
      }
    }
  }
}

// =====================================================================
extern "C" void kernel_launch(void* const* d_in, const int* in_sizes, int n_in,
                              void* d_out, int out_size, void* d_ws, size_t ws_size,
                              hipStream_t stream) {
  // setup_inputs order: x, Wq, bq, Wk, bk, Wv, bv, Wp, bp
  const float* x  = (const float*)d_in[0];
  const float* Wv = (const float*)d_in[5];
  const float* bv = (const float*)d_in[6];
  const float* Wp = (const float*)d_in[7];
  const float* bp = (const float*)d_in[8];

  char* ws = (char*)d_ws;
  u16* wpb   = (u16*)(ws + (16u << 20));        //  2 MB  Wp bf16
  u16* wvtb  = (u16*)(ws + (18u << 20));        //  2 MB  Wv^T bf16
  u16* m2b   = (u16*)(ws + (20u << 20));        //  2 MB  M2 bf16
  float* cv  = (float*)(ws + (22u << 20));      //  4 KB  folded bias

  // 1) slim prep: conv Wp / transpose Wv / bias fold
  k_prep<<<2304, 256, 0, stream>>>(Wv, bv, Wp, bp, wpb, wvtb, cv);

  // 2) M2 = bf16(2048 * Wp @ Wv)  (64^2 tiles: 256 blocks, 16 iters)
  k_gemm<1><<<256, 256, 0, stream>>>(wpb, wvtb, m2b, nullptr, 1024, 1024, 1024);

  // 3) out = x @ M2^T + cv  (fused f32->bf16 A-staging; 512 blocks)
  k_gemm<0><<<512, 512, 0, stream>>>(x, m2b, d_out, cv, 8192, 1024, 1024);
}

// Round 7
// 148.689 us; speedup vs baseline: 1.0092x; 1.0092x over previous
//
#include <hip/hip_runtime.h>
#include <cstdint>

// =====================================================================
// MultiHeadAttention_84576495993495  (round 14)
//
// Algebraic collapse: einsum('bhqk,bhvo->bhvo', attn, v) sums attn over
// BOTH q and k; softmax rows sum to 1 -> factor is exactly S=2048.
//   final = x @ (2048*Wp@Wv)^T + (2048*Wp@bv + bp)
// Wq/bq/Wk/bk unused.
//
// R14 theory (R13 counters: gemm0 46us, MfmaUtil 13%, VALU 16%, HBM
// 16%, occ 28% -- pure latency-bound): R13's A-chain (f32 load at top
// of iter t, ds_write at END of iter t) exposes ~500cyc of HBM latency
// per iter. Fix (T14 with correct distance):
//   - ds_write of A(t+1) moves to TOP of iter t (WAR-safe: end-of-
//     (t-1) barrier guarantees buf[cur^1] is no longer being read).
//     A(t+1) regs were loaded mid-iter t-1 -> load->use gap ~1 full
//     iter (>900cyc HBM latency), single reg set (16 VGPR).
//   - end-of-iter wait now COUNTED: vmcnt(4) = B(t+1) glds done
//     (L2-resident, covered by MFMA); A(t+2)'s 4 loads stay in
//     flight across the barrier. Never vmcnt(0) mid-loop.
// Everything else unchanged from R13 (swizzle contract, XCD grouping,
// MODE1 gemm1, slim prep).
// =====================================================================

typedef unsigned short u16;
typedef __bf16 bf16x8 __attribute__((ext_vector_type(8)));
typedef float f32x4 __attribute__((ext_vector_type(4)));

__device__ __forceinline__ u16 f2bf(float f) {
  // round-to-nearest-even f32 -> bf16 bits (finite inputs)
  unsigned int u = __float_as_uint(f);
  u += 0x7fffu + ((u >> 16) & 1u);
  return (u16)(u >> 16);
}

__device__ __forceinline__ bf16x8 cvt8(float4 a, float4 b) {
  bf16x8 r;
  r[0] = (__bf16)a.x; r[1] = (__bf16)a.y; r[2] = (__bf16)a.z; r[3] = (__bf16)a.w;
  r[4] = (__bf16)b.x; r[5] = (__bf16)b.y; r[6] = (__bf16)b.z; r[7] = (__bf16)b.w;
  return r;
}

// async global->LDS 16B copy; LDS dest = wave-uniform base + lane*16
__device__ __forceinline__ void load16(const void* g, void* l) {
  auto gp = (const __attribute__((address_space(1))) unsigned int*)(uintptr_t)g;
  auto lp = (__attribute__((address_space(3))) unsigned int*)(unsigned int)(uintptr_t)l;
  __builtin_amdgcn_global_load_lds(gp, lp, 16, 0, 0);
}

// ---------------------------------------------------------------------
// Slim prep. Block ranges:
//   [0,1024)     conv Wp  f32->bf16 (4 elem/thread)
//   [1024,2048)  transpose+conv Wv -> Wv^T bf16 (32x32 tiles)
//   [2048,2304)  cv[n] = 2048*dot(Wp[n,:],bv) + bp[n]
__global__ void k_prep(const float* __restrict__ Wv, const float* __restrict__ bv,
                       const float* __restrict__ Wp, const float* __restrict__ bp,
                       u16* __restrict__ wpb, u16* __restrict__ wvtb,
                       float* __restrict__ cv) {
  __shared__ float tile[32][33];
  const int b = blockIdx.x;
  const int tid = threadIdx.x;
  if (b < 1024) {  // conv Wp
    const long base = (long)b * 1024 + tid * 4;
    const float4 v = *(const float4*)(Wp + base);
    ushort4 o;
    o.x = f2bf(v.x); o.y = f2bf(v.y); o.z = f2bf(v.z); o.w = f2bf(v.w);
    *(ushort4*)(wpb + base) = o;
  } else if (b < 2048) {  // transpose Wv
    const int tb = b - 1024;
    const int bi = (tb & 31) * 32;   // output row block (i)
    const int bj = (tb >> 5) * 32;   // output col block (j) = src row block
    const int tx = tid & 31;
    const int ty = tid >> 5;  // 0..7
    for (int r = ty; r < 32; r += 8)
      tile[r][tx] = Wv[(long)(bj + r) * 1024 + bi + tx];
    __syncthreads();
    for (int r = ty; r < 32; r += 8)
      wvtb[(long)(bi + r) * 1024 + bj + tx] = f2bf(tile[tx][r]);
  } else {  // bias fold
    const int row = (b - 2048) * 4 + (tid >> 6);
    const int lane = tid & 63;
    const float* w = Wp + (long)row * 1024;
    float s = 0.f;
    for (int j = lane; j < 1024; j += 64) s += w[j] * bv[j];
    for (int off = 32; off; off >>= 1) s += __shfl_down(s, off, 64);
    if (lane == 0) cv[row] = 2048.f * s + bp[row];
  }
}

// ---------------------------------------------------------------------
// NT bf16 GEMM: Out[M,N] = A[M,K] @ B[N,K]^T  (+bias or *2048->bf16)
// LDS contract: 64 u16/row, slot c of row r holds logical chunk
// c ^ (r&7); fragment ds_read_b128 aliases 2-way (free, m136).
// MODE 0: A is f32 (x), reg-staged with fused cvt. Pipeline:
//   iter t: [ds_write A(t+1) from regs loaded @t-1] [B glds(t+1)]
//           [load A(t+2)->regs] -> frag reads -> lgkmcnt(0) -> MFMA ->
//           vmcnt(4) (A(t+2) stays in flight) -> barrier.
//   BM=BN=128, 512 thr = 8 waves (2Mx4N, wave 64x32, acc 4x2), f32
//   out + bias, XCD-grouped 512-block grid, 64 KB LDS.
// MODE 1: A,B bf16 via global_load_lds, drain-after-MFMA (R12 form).
//   BM=BN=64, 256 thr = 4 waves (2x2, wave 32x32), bf16 out * 2048.
template <int MODE>
__global__ __launch_bounds__(MODE == 0 ? 512 : 256) void k_gemm(
    const void* __restrict__ Ain, const u16* __restrict__ B, void* __restrict__ OutV,
    const float* __restrict__ bias, int M, int N, int K) {
  constexpr int BM = (MODE == 0) ? 128 : 64;
  constexpr int BN = (MODE == 0) ? 128 : 64;
  constexpr int T  = (MODE == 0) ? 512 : 256;
  constexpr int WTM = (MODE == 0) ? 64 : 32;  // wave tile M
  constexpr int WTN = 32;                      // wave tile N
  constexpr int AccM = WTM / 16;               // 4 or 2
  constexpr int AccN = WTN / 16;               // 2

  __shared__ u16 As[2][BM * 64];
  __shared__ u16 Bs[2][BN * 64];

  const int tid = threadIdx.x;
  const int lane = tid & 63;
  const int wv = tid >> 6;
  const int waveM = (wv & 1) * WTM;
  const int waveN = (wv >> 1) * WTN;
  const int l15 = lane & 15;
  const int quad = lane >> 4;

  long bm, bn;
  if constexpr (MODE == 0) {
    // XCD grouping: xcd = id&7 owns 8 contiguous m-panels; a panel's 8
    // n-blocks are temporally adjacent on that XCD (B = 2 MB L2-fits).
    const int id = blockIdx.x;            // gridDim.x = (M/128)*(N/128)
    const int xcd = id & 7;
    const int j = id >> 3;
    const int nb = N >> 7;
    const int mPerXcd = M / 128 / 8;
    bm = (long)(xcd * mPerXcd + j / nb) * 128;
    bn = (long)(j % nb) * 128;
  } else {
    bm = (long)(blockIdx.x >> 4) * 64;
    bn = (long)(blockIdx.x & 15) * 64;
  }

  const int nT = K >> 6;  // # K-tiles (16 for K=1024)

  // ---- B staging via global_load_lds (both modes) ----
  // Thread t: row = t>>3, LDS slot = t&7, global chunk = (t&7)^(row&7).
  const int rl = tid >> 3;
  const int cs = (tid & 7) ^ (rl & 7);
  const u16* Bg0 = B + (bn + rl) * (long)K + cs * 8;
  constexpr int RPC = T / 8;  // rows per glds call (64 or 32)

  // ---- A staging ----
  const float* Afg = nullptr;  // MODE 0: f32 x
  const u16* Ag0 = nullptr;    // MODE 1: bf16
  int ar = 0, as0 = 0, as1 = 0;
  if constexpr (MODE == 0) {
    const float* Af = (const float*)Ain;
    ar = tid >> 2;                       // row 0..127
    const int ap = tid & 3;              // chunk-pair index
    Afg = Af + (bm + ar) * (long)K + ap * 16;
    as0 = ((2 * ap)     ^ (ar & 7)) * 8;  // u16 offset of swizzled slot
    as1 = ((2 * ap + 1) ^ (ar & 7)) * 8;
  } else {
    Ag0 = (const u16*)Ain + (bm + rl) * (long)K + cs * 8;
  }

  const f32x4 zero = {0.f, 0.f, 0.f, 0.f};
  f32x4 acc[AccM][AccN];
#pragma unroll
  for (int i = 0; i < AccM; ++i)
#pragma unroll
    for (int j = 0; j < AccN; ++j) acc[i][j] = zero;

  // Fragment read slots (swizzled): logical chunk kk*4+quad of row
  // (..+l15) sits at slot ^ (l15&7)  (base rows are multiples of 8).
  const int rq0 = quad ^ (l15 & 7);        // kk = 0
  const int rq1 = (4 + quad) ^ (l15 & 7);  // kk = 1

  float4 va0, va1, va2, va3;  // A reg set (MODE 0): holds tile t+1

  // ---- prologue ----
  if constexpr (MODE == 0) {
    // load + write A(0); stage B(0); load A(1) into regs
    va0 = *(const float4*)(Afg + 0);
    va1 = *(const float4*)(Afg + 4);
    va2 = *(const float4*)(Afg + 8);
    va3 = *(const float4*)(Afg + 12);
    u16* Aw = &As[0][0] + ar * 64;
    *(bf16x8*)(Aw + as0) = cvt8(va0, va1);   // compiler waits A(0) regs
    *(bf16x8*)(Aw + as1) = cvt8(va2, va3);
    u16* Bd = &Bs[0][0] + tid * 8;
    load16(Bg0, Bd);
    load16(Bg0 + (long)RPC * K, Bd + RPC * 64);
    va0 = *(const float4*)(Afg + 64 + 0);    // tile 1 (K-offset 64 f32)
    va1 = *(const float4*)(Afg + 64 + 4);
    va2 = *(const float4*)(Afg + 64 + 8);
    va3 = *(const float4*)(Afg + 64 + 12);
    // B(0) done (A(1)'s 4 loads stay in flight); ds_writes drained
    asm volatile("s_waitcnt vmcnt(4) lgkmcnt(0)" ::: "memory");
  } else {
    u16* Ad = &As[0][0] + tid * 8;
    u16* Bd = &Bs[0][0] + tid * 8;
    load16(Ag0, Ad);
    load16(Ag0 + (long)RPC * K, Ad + RPC * 64);
    load16(Bg0, Bd);
    load16(Bg0 + (long)RPC * K, Bd + RPC * 64);
    asm volatile("s_waitcnt vmcnt(0)" ::: "memory");
  }
  __builtin_amdgcn_s_barrier();

  int cur = 0;
  for (int t = 0; t < nT; ++t) {
    const bool w1 = (t + 1) < nT;
    const bool w2 = (t + 2) < nT;
    const long k1 = (long)(t + 1) << 6;

    if constexpr (MODE == 0) {
      if (w1) {
        // write A(t+1) (regs loaded @ iter t-1: >1 iter old, landed).
        // WAR-safe: end-of-(t-1) barrier ended all reads of buf cur^1.
        u16* Aw = &As[cur ^ 1][0] + ar * 64;
        *(bf16x8*)(Aw + as0) = cvt8(va0, va1);
        *(bf16x8*)(Aw + as1) = cvt8(va2, va3);
        u16* Bd = &Bs[cur ^ 1][0] + tid * 8;
        load16(Bg0 + k1, Bd);
        load16(Bg0 + k1 + (long)RPC * K, Bd + RPC * 64);
      }
      if (w2) {
        const float* ag = Afg + ((long)(t + 2) << 6);
        va0 = *(const float4*)(ag + 0);
        va1 = *(const float4*)(ag + 4);
        va2 = *(const float4*)(ag + 8);
        va3 = *(const float4*)(ag + 12);
      }
    } else {
      if (w1) {
        u16* Ad = &As[cur ^ 1][0] + tid * 8;
        u16* Bd = &Bs[cur ^ 1][0] + tid * 8;
        load16(Ag0 + k1, Ad);
        load16(Ag0 + k1 + (long)RPC * K, Ad + RPC * 64);
        load16(Bg0 + k1, Bd);
        load16(Bg0 + k1 + (long)RPC * K, Bd + RPC * 64);
      }
    }
    __builtin_amdgcn_sched_barrier(0);  // keep stage issue ahead of reads

    const u16* Asb = &As[cur][0];
    const u16* Bsb = &Bs[cur][0];
    bf16x8 af[2][AccM], bg[2][AccN];
#pragma unroll
    for (int i = 0; i < AccM; ++i) {
      const int ra = (waveM + i * 16 + l15) * 64;
      af[0][i] = *(const bf16x8*)(Asb + ra + rq0 * 8);
      af[1][i] = *(const bf16x8*)(Asb + ra + rq1 * 8);
    }
#pragma unroll
    for (int j = 0; j < AccN; ++j) {
      const int rb = (waveN + j * 16 + l15) * 64;
      bg[0][j] = *(const bf16x8*)(Bsb + rb + rq0 * 8);
      bg[1][j] = *(const bf16x8*)(Bsb + rb + rq1 * 8);
    }
    // drains frag reads AND this iter's ds_writes (visible by barrier)
    asm volatile("s_waitcnt lgkmcnt(0)" ::: "memory");
    __builtin_amdgcn_sched_barrier(0);  // rule #18: no MFMA hoist past wait

#pragma unroll
    for (int kk = 0; kk < 2; ++kk)
#pragma unroll
      for (int i = 0; i < AccM; ++i)
#pragma unroll
        for (int j = 0; j < AccN; ++j)
          acc[i][j] = __builtin_amdgcn_mfma_f32_16x16x32_bf16(af[kk][i], bg[kk][j],
                                                              acc[i][j], 0, 0, 0);

    if (w1) {
      if constexpr (MODE == 0) {
        if (w2) {
          // counted: B(t+1)'s 2 glds done; A(t+2)'s 4 stay in flight
          asm volatile("s_waitcnt vmcnt(4)" ::: "memory");
        } else {
          asm volatile("s_waitcnt vmcnt(0)" ::: "memory");
        }
      } else {
        asm volatile("s_waitcnt vmcnt(0)" ::: "memory");
      }
      __builtin_amdgcn_s_barrier();
      cur ^= 1;
    }
  }

  // epilogue: C/D layout col = lane&15, row = quad*4 + reg  [m89/m91]
#pragma unroll
  for (int i = 0; i < AccM; ++i) {
    const long gm = bm + waveM + i * 16 + quad * 4;
#pragma unroll
    for (int j = 0; j < AccN; ++j) {
      const long gn = bn + waveN + j * 16 + l15;
      if constexpr (MODE == 0) {
        float* outp = (float*)OutV;
        const float bb = bias[gn];
#pragma unroll
        for (int r = 0; r < 4; ++r)
          outp[(gm + r) * N + gn] = acc[i][j][r] + bb;
      } else {
        u16* outp = (u16*)OutV;
#pragma unroll
        for (int r = 0; r < 4; ++r)
          outp[(gm + r) * N + gn] = f2bf(acc[i][j][r] * 2048.f);
      }
    }
  }
}

// =====================================================================
extern "C" void kernel_launch(void* const* d_in, const int* in_sizes, int n_in,
                              void* d_out, int out_size, void* d_ws, size_t ws_size,
                              hipStream_t stream) {
  // setup_inputs order: x, Wq, bq, Wk, bk, Wv, bv, Wp, bp
  const float* x  = (const float*)d_in[0];
  const float* Wv = (const float*)d_in[5];
  const float* bv = (const float*)d_in[6];
  const float* Wp = (const float*)d_in[7];
  const float* bp = (const float*)d_in[8];

  char* ws = (char*)d_ws;
  u16* wpb   = (u16*)(ws + (16u << 20));        //  2 MB  Wp bf16
  u16* wvtb  = (u16*)(ws + (18u << 20));        //  2 MB  Wv^T bf16
  u16* m2b   = (u16*)(ws + (20u << 20));        //  2 MB  M2 bf16
  float* cv  = (float*)(ws + (22u << 20));      //  4 KB  folded bias

  // 1) slim prep: conv Wp / transpose Wv / bias fold
  k_prep<<<2304, 256, 0, stream>>>(Wv, bv, Wp, bp, wpb, wvtb, cv);

  // 2) M2 = bf16(2048 * Wp @ Wv)  (64^2 tiles: 256 blocks, 16 iters)
  k_gemm<1><<<256, 256, 0, stream>>>(wpb, wvtb, m2b, nullptr, 1024, 1024, 1024);

  // 3) out = x @ M2^T + cv  (fused f32->bf16 A-staging; 512 blocks)
  k_gemm<0><<<512, 512, 0, stream>>>(x, m2b, d_out, cv, 8192, 1024, 1024);
}

// Round 8
// 147.868 us; speedup vs baseline: 1.0148x; 1.0056x over previous
//
#include <hip/hip_runtime.h>
#include <cstdint>

// =====================================================================
// MultiHeadAttention_84576495993495  (round 15)
//
// Algebraic collapse: einsum('bhqk,bhvo->bhvo', attn, v) sums attn over
// BOTH q and k; softmax rows sum to 1 -> factor is exactly S=2048.
//   final = x @ (2048*Wp@Wv)^T + (2048*Wp@bv + bp)
// Wq/bq/Wk/bk unused.
//
// R15 theory: every gemm0 so far ran 2 blocks/CU BY GRID (512 x 128^2
// tiles / 256 CU) -- the m97 ladder's latency hiding is CROSS-BLOCK
// overlap at 4 blocks/CU (m114); in-block waves are barrier-convoyed
// (R12 proved more waves/block is ~null; R13/R14's fused-A lost ~10us
// -> abandoned). Isolate residency:
//   - gemm0: 128x64 tile, BK=32, 256 thr / 4 waves (wave 64x32),
//     24 KB LDS -> grid 1024 = 4 independent blocks/CU.
//   - Schedule: proven R10/R12 2-phase (STAGE(t+1) -> ds_read ->
//     lgkmcnt(0) -> MFMA -> vmcnt(0) -> barrier). glds both operands.
//   - Swizzle: 4-chunk rows, slot s of row r holds chunk s^((r>>1)&3)
//     -> ds_read_b128 2-way (free, m136); inverse perm on glds source.
//   - prep restored to full (x f32->bf16); gemm1 = R12 MODE1 verbatim.
// Rule: gemm0 >=38us -> residency null -> revert R12, declare floor.
// =====================================================================

typedef unsigned short u16;
typedef __bf16 bf16x8 __attribute__((ext_vector_type(8)));
typedef float f32x4 __attribute__((ext_vector_type(4)));

__device__ __forceinline__ u16 f2bf(float f) {
  // round-to-nearest-even f32 -> bf16 bits (finite inputs)
  unsigned int u = __float_as_uint(f);
  u += 0x7fffu + ((u >> 16) & 1u);
  return (u16)(u >> 16);
}

// async global->LDS 16B copy; LDS dest = wave-uniform base + lane*16
__device__ __forceinline__ void load16(const void* g, void* l) {
  auto gp = (const __attribute__((address_space(1))) unsigned int*)(uintptr_t)g;
  auto lp = (__attribute__((address_space(3))) unsigned int*)(unsigned int)(uintptr_t)l;
  __builtin_amdgcn_global_load_lds(gp, lp, 16, 0, 0);
}

// ---------------------------------------------------------------------
// Fused prep. Block ranges:
//   [0,8192)      conv x   f32->bf16 (4 elem/thread)
//   [8192,9216)   conv Wp  f32->bf16
//   [9216,10240)  transpose+conv Wv -> Wv^T bf16 (32x32 tiles)
//   [10240,10496) cv[n] = 2048*dot(Wp[n,:],bv) + bp[n]
__global__ void k_prep(const float* __restrict__ x, const float* __restrict__ Wv,
                       const float* __restrict__ bv, const float* __restrict__ Wp,
                       const float* __restrict__ bp, u16* __restrict__ xb,
                       u16* __restrict__ wpb, u16* __restrict__ wvtb,
                       float* __restrict__ cv) {
  __shared__ float tile[32][33];
  const int b = blockIdx.x;
  const int tid = threadIdx.x;
  if (b < 9216) {  // conversions
    const float* src = (b < 8192) ? x : Wp;
    u16* dst = (b < 8192) ? xb : wpb;
    const long base = (long)((b < 8192) ? b : (b - 8192)) * 1024 + tid * 4;
    const float4 v = *(const float4*)(src + base);
    ushort4 o;
    o.x = f2bf(v.x); o.y = f2bf(v.y); o.z = f2bf(v.z); o.w = f2bf(v.w);
    *(ushort4*)(dst + base) = o;
  } else if (b < 10240) {  // transpose Wv
    const int tb = b - 9216;
    const int bi = (tb & 31) * 32;   // output row block (i)
    const int bj = (tb >> 5) * 32;   // output col block (j) = src row block
    const int tx = tid & 31;
    const int ty = tid >> 5;  // 0..7
    for (int r = ty; r < 32; r += 8)
      tile[r][tx] = Wv[(long)(bj + r) * 1024 + bi + tx];
    __syncthreads();
    for (int r = ty; r < 32; r += 8)
      wvtb[(long)(bi + r) * 1024 + bj + tx] = f2bf(tile[tx][r]);
  } else {  // bias fold
    const int row = (b - 10240) * 4 + (tid >> 6);
    const int lane = tid & 63;
    const float* w = Wp + (long)row * 1024;
    float s = 0.f;
    for (int j = lane; j < 1024; j += 64) s += w[j] * bv[j];
    for (int off = 32; off; off >>= 1) s += __shfl_down(s, off, 64);
    if (lane == 0) cv[row] = 2048.f * s + bp[row];
  }
}

// ---------------------------------------------------------------------
// gemm0: Out[M,N] f32 = A[M,K]bf16 @ B[N,K]^T bf16 + bias
// 128x64 tile, BK=32, 256 thr = 4 waves (2Mx2N), wave tile 64x32
// (acc 4x2, 8 MFMA/iter). LDS 24 KB -> 4 blocks/CU at grid 1024.
// LDS rows = 32 u16 (4 chunks x 16B); slot s of row r holds logical
// chunk s ^ ((r>>1)&3)  (2-way ds_read conflict = free).
// Schedule: 2-phase, drain-after-MFMA (R10/R12 verified).
__global__ __launch_bounds__(256) void k_gemm0(
    const u16* __restrict__ A, const u16* __restrict__ B, float* __restrict__ Out,
    const float* __restrict__ bias, int M, int N, int K) {
  __shared__ u16 As[2][128 * 32];  // 2 x 8 KB
  __shared__ u16 Bs[2][64 * 32];   // 2 x 4 KB

  const int tid = threadIdx.x;
  const int lane = tid & 63;
  const int wv = tid >> 6;
  const int waveM = (wv & 1) << 6;   // 0 / 64
  const int waveN = (wv >> 1) << 5;  // 0 / 32
  const int l15 = lane & 15;
  const int quad = lane >> 4;

  // XCD grouping over 1024 blocks: xcd = id&7 owns m-panels
  // [xcd*8, +8), each panel's 16 n-blocks temporally adjacent.
  const int id = blockIdx.x;
  const int xcd = id & 7;
  const int j = id >> 3;                 // 0..127
  const long bm = (long)(xcd * 8 + (j >> 4)) * 128;
  const long bn = (long)(j & 15) * 64;

  // Staging: lane l -> row_local = l>>2, LDS slot = l&3,
  // global chunk cs = (l&3) ^ ((l>>3)&3)  [= slot ^ ((row>>1)&3)].
  // A: 2 glds/wave (row groups wv, 4+wv); B: 1 glds/wave (group wv).
  const int rl = lane >> 2;
  const int cs = (lane & 3) ^ ((lane >> 3) & 3);
  const u16* Ag0 = A + (bm + wv * 16 + rl) * (long)K + cs * 8;
  const u16* Bg0 = B + (bn + wv * 16 + rl) * (long)K + cs * 8;
  const long rowOff = 64 * (long)K;  // A call r=1: +64 rows

  const int nT = K >> 5;  // 32 K-tiles

  auto STAGE = [&](long k0, int b) {
    u16* Ad = &As[b][0] + (wv << 9);         // group wv (1 KB)
    u16* Bd = &Bs[b][0] + (wv << 9);
    load16(Ag0 + k0, Ad);
    load16(Ag0 + rowOff + k0, Ad + 2048);    // group 4+wv
    load16(Bg0 + k0, Bd);
  };

  const f32x4 zero = {0.f, 0.f, 0.f, 0.f};
  f32x4 acc[4][2];
#pragma unroll
  for (int i = 0; i < 4; ++i)
#pragma unroll
    for (int j2 = 0; j2 < 2; ++j2) acc[i][j2] = zero;

  // Fragment read: logical chunk quad of row (..+l15) at slot
  // quad ^ ((l15>>1)&3)  (base rows are multiples of 8).
  const int rq = quad ^ ((l15 >> 1) & 3);

  // ---- prologue ----
  STAGE(0, 0);
  asm volatile("s_waitcnt vmcnt(0)" ::: "memory");
  __builtin_amdgcn_s_barrier();

  int cur = 0;
  for (int t = 0; t < nT; ++t) {
    const bool more = (t + 1) < nT;
    if (more) STAGE((long)(t + 1) << 5, cur ^ 1);
    __builtin_amdgcn_sched_barrier(0);  // keep stage issue ahead of reads

    const u16* Asb = &As[cur][0];
    const u16* Bsb = &Bs[cur][0];
    bf16x8 af[4], bg[2];
#pragma unroll
    for (int i = 0; i < 4; ++i)
      af[i] = *(const bf16x8*)(Asb + (waveM + i * 16 + l15) * 32 + rq * 8);
#pragma unroll
    for (int j2 = 0; j2 < 2; ++j2)
      bg[j2] = *(const bf16x8*)(Bsb + (waveN + j2 * 16 + l15) * 32 + rq * 8);
    asm volatile("s_waitcnt lgkmcnt(0)" ::: "memory");
    __builtin_amdgcn_sched_barrier(0);  // rule #18: no MFMA hoist past wait

#pragma unroll
    for (int i = 0; i < 4; ++i)
#pragma unroll
      for (int j2 = 0; j2 < 2; ++j2)
        acc[i][j2] = __builtin_amdgcn_mfma_f32_16x16x32_bf16(af[i], bg[j2],
                                                             acc[i][j2], 0, 0, 0);

    if (more) {
      asm volatile("s_waitcnt vmcnt(0)" ::: "memory");
      __builtin_amdgcn_s_barrier();
      cur ^= 1;
    }
  }

  // epilogue: C/D layout col = lane&15, row = quad*4 + reg  [m89/m91]
#pragma unroll
  for (int i = 0; i < 4; ++i) {
    const long gm = bm + waveM + i * 16 + quad * 4;
#pragma unroll
    for (int j2 = 0; j2 < 2; ++j2) {
      const long gn = bn + waveN + j2 * 16 + l15;
      const float bb = bias[gn];
#pragma unroll
      for (int r = 0; r < 4; ++r)
        Out[(gm + r) * N + gn] = acc[i][j2][r] + bb;
    }
  }
}

// ---------------------------------------------------------------------
// gemm1 (R12 MODE1 verbatim): M2 = bf16(2048 * Wp @ Wv^T-input)
// 64x64 tile, BK=64, 256 thr = 4 waves (2x2, wave 32x32, acc 2x2),
// glds both operands, drain-after-MFMA, 256-block grid, 32 KB LDS.
__global__ __launch_bounds__(256) void k_gemm1(
    const u16* __restrict__ A, const u16* __restrict__ B, u16* __restrict__ Out,
    int M, int N, int K) {
  __shared__ u16 As[2][64 * 64];  // 2 x 8 KB
  __shared__ u16 Bs[2][64 * 64];  // 2 x 8 KB

  const int tid = threadIdx.x;
  const int lane = tid & 63;
  const int wv = tid >> 6;
  const int waveM = (wv & 1) << 5;
  const int waveN = (wv >> 1) << 5;
  const int l15 = lane & 15;
  const int quad = lane >> 4;

  const long bm = (long)(blockIdx.x >> 4) * 64;
  const long bn = (long)(blockIdx.x & 15) * 64;

  // Thread t: row = t>>3, LDS slot = t&7, global chunk = (t&7)^(row&7).
  const int rl = tid >> 3;
  const int cs = (tid & 7) ^ (rl & 7);
  const u16* Ag0 = A + (bm + rl) * (long)K + cs * 8;
  const u16* Bg0 = B + (bn + rl) * (long)K + cs * 8;
  constexpr int RPC = 32;  // rows per glds call

  const int nT = K >> 6;  // 16 K-tiles

  auto STAGE = [&](long k0, int b) {
    u16* Ad = &As[b][0] + tid * 8;
    u16* Bd = &Bs[b][0] + tid * 8;
    load16(Ag0 + k0, Ad);
    load16(Ag0 + k0 + (long)RPC * K, Ad + RPC * 64);
    load16(Bg0 + k0, Bd);
    load16(Bg0 + k0 + (long)RPC * K, Bd + RPC * 64);
  };

  const f32x4 zero = {0.f, 0.f, 0.f, 0.f};
  f32x4 acc[2][2];
#pragma unroll
  for (int i = 0; i < 2; ++i)
#pragma unroll
    for (int j = 0; j < 2; ++j) acc[i][j] = zero;

  const int rq0 = quad ^ (l15 & 7);        // kk = 0
  const int rq1 = (4 + quad) ^ (l15 & 7);  // kk = 1

  STAGE(0, 0);
  asm volatile("s_waitcnt vmcnt(0)" ::: "memory");
  __builtin_amdgcn_s_barrier();

  int cur = 0;
  for (int t = 0; t < nT; ++t) {
    const bool more = (t + 1) < nT;
    if (more) STAGE((long)(t + 1) << 6, cur ^ 1);
    __builtin_amdgcn_sched_barrier(0);

    const u16* Asb = &As[cur][0];
    const u16* Bsb = &Bs[cur][0];
    bf16x8 af[2][2], bg[2][2];
#pragma unroll
    for (int i = 0; i < 2; ++i) {
      const int ra = (waveM + i * 16 + l15) * 64;
      af[0][i] = *(const bf16x8*)(Asb + ra + rq0 * 8);
      af[1][i] = *(const bf16x8*)(Asb + ra + rq1 * 8);
    }
#pragma unroll
    for (int j = 0; j < 2; ++j) {
      const int rb = (waveN + j * 16 + l15) * 64;
      bg[0][j] = *(const bf16x8*)(Bsb + rb + rq0 * 8);
      bg[1][j] = *(const bf16x8*)(Bsb + rb + rq1 * 8);
    }
    asm volatile("s_waitcnt lgkmcnt(0)" ::: "memory");
    __builtin_amdgcn_sched_barrier(0);

#pragma unroll
    for (int kk = 0; kk < 2; ++kk)
#pragma unroll
      for (int i = 0; i < 2; ++i)
#pragma unroll
        for (int j = 0; j < 2; ++j)
          acc[i][j] = __builtin_amdgcn_mfma_f32_16x16x32_bf16(af[kk][i], bg[kk][j],
                                                              acc[i][j], 0, 0, 0);

    if (more) {
      asm volatile("s_waitcnt vmcnt(0)" ::: "memory");
      __builtin_amdgcn_s_barrier();
      cur ^= 1;
    }
  }

#pragma unroll
  for (int i = 0; i < 2; ++i) {
    const long gm = bm + waveM + i * 16 + quad * 4;
#pragma unroll
    for (int j = 0; j < 2; ++j) {
      const long gn = bn + waveN + j * 16 + l15;
#pragma unroll
      for (int r = 0; r < 4; ++r)
        Out[(gm + r) * N + gn] = f2bf(acc[i][j][r] * 2048.f);
    }
  }
}

// =====================================================================
extern "C" void kernel_launch(void* const* d_in, const int* in_sizes, int n_in,
                              void* d_out, int out_size, void* d_ws, size_t ws_size,
                              hipStream_t stream) {
  // setup_inputs order: x, Wq, bq, Wk, bk, Wv, bv, Wp, bp
  const float* x  = (const float*)d_in[0];
  const float* Wv = (const float*)d_in[5];
  const float* bv = (const float*)d_in[6];
  const float* Wp = (const float*)d_in[7];
  const float* bp = (const float*)d_in[8];

  char* ws = (char*)d_ws;
  u16* xb    = (u16*)(ws);                      // 16 MB  x bf16
  u16* wpb   = (u16*)(ws + (16u << 20));        //  2 MB  Wp bf16
  u16* wvtb  = (u16*)(ws + (18u << 20));        //  2 MB  Wv^T bf16
  u16* m2b   = (u16*)(ws + (20u << 20));        //  2 MB  M2 bf16
  float* cv  = (float*)(ws + (22u << 20));      //  4 KB  folded bias

  // 1) fused prep: conv x / conv Wp / transpose Wv / bias fold
  k_prep<<<10496, 256, 0, stream>>>(x, Wv, bv, Wp, bp, xb, wpb, wvtb, cv);

  // 2) M2 = bf16(2048 * Wp @ Wv)  (64^2 tiles: 256 blocks, 16 iters)
  k_gemm1<<<256, 256, 0, stream>>>(wpb, wvtb, m2b, 1024, 1024, 1024);

  // 3) out = x @ M2^T + cv  (128x64 tiles: 1024 blocks = 4/CU)
  k_gemm0<<<1024, 256, 0, stream>>>(xb, m2b, (float*)d_out, cv,
                                    8192, 1024, 1024);
}

// Round 9
// 143.402 us; speedup vs baseline: 1.0464x; 1.0311x over previous
//
#include <hip/hip_runtime.h>
#include <cstdint>

// =====================================================================
// MultiHeadAttention_84576495993495  (round 16)
//
// Algebraic collapse: einsum('bhqk,bhvo->bhvo', attn, v) sums attn over
// BOTH q and k; softmax rows sum to 1 -> factor is exactly S=2048.
//   final = x @ (2048*Wp@Wv)^T + (2048*Wp@bv + bp)
// Wq/bq/Wk/bk unused.
//
// R16: the only untried lever with verified headroom is the 8-phase
// fine interleave itself (T3+T4; m196/m198: +28-41% over 2-phase;
// prerequisite for T5). gemm0 ported to the m201 phase anatomy:
//   - BM=256 BN=128 BK=64, grid 256 (1 block/CU), 512 thr = 8 waves
//     (2Mx4N, wave tile 128x32, acc 8x2).
//   - 3 LDS buffers (3 x 48 KB = 144 KB): read t, t+1 resident, stage
//     t+2 -- distinct mod 3, NO intra-buffer races (simpler than
//     m201's 2-buffer overlap); WAR-safe via end-of-iter barrier.
//   - per K-tile: 2 phases x {12 ds_read + 3 stage-issues ->
//     s_barrier -> lgkmcnt(0) -> setprio(1)+16 MFMA+setprio(0) ->
//     s_barrier}; counted vmcnt(6) ONCE per tile (t+2 stays in
//     flight across the barrier; never 0 mid-loop).
//   - swizzle contract unchanged (slot c of row r holds chunk
//     c^(r&7); inverse perm on glds source; 2-way = free).
// gemm1 + prep = R12/R15 verbatim.
// Rule: total >=137us -> 8-phase null at this shape -> declare floor.
// =====================================================================

typedef unsigned short u16;
typedef __bf16 bf16x8 __attribute__((ext_vector_type(8)));
typedef float f32x4 __attribute__((ext_vector_type(4)));

__device__ __forceinline__ u16 f2bf(float f) {
  // round-to-nearest-even f32 -> bf16 bits (finite inputs)
  unsigned int u = __float_as_uint(f);
  u += 0x7fffu + ((u >> 16) & 1u);
  return (u16)(u >> 16);
}

// async global->LDS 16B copy; LDS dest = wave-uniform base + lane*16
__device__ __forceinline__ void load16(const void* g, void* l) {
  auto gp = (const __attribute__((address_space(1))) unsigned int*)(uintptr_t)g;
  auto lp = (__attribute__((address_space(3))) unsigned int*)(unsigned int)(uintptr_t)l;
  __builtin_amdgcn_global_load_lds(gp, lp, 16, 0, 0);
}

// ---------------------------------------------------------------------
// Fused prep. Block ranges:
//   [0,8192)      conv x   f32->bf16 (4 elem/thread)
//   [8192,9216)   conv Wp  f32->bf16
//   [9216,10240)  transpose+conv Wv -> Wv^T bf16 (32x32 tiles)
//   [10240,10496) cv[n] = 2048*dot(Wp[n,:],bv) + bp[n]
__global__ void k_prep(const float* __restrict__ x, const float* __restrict__ Wv,
                       const float* __restrict__ bv, const float* __restrict__ Wp,
                       const float* __restrict__ bp, u16* __restrict__ xb,
                       u16* __restrict__ wpb, u16* __restrict__ wvtb,
                       float* __restrict__ cv) {
  __shared__ float tile[32][33];
  const int b = blockIdx.x;
  const int tid = threadIdx.x;
  if (b < 9216) {  // conversions
    const float* src = (b < 8192) ? x : Wp;
    u16* dst = (b < 8192) ? xb : wpb;
    const long base = (long)((b < 8192) ? b : (b - 8192)) * 1024 + tid * 4;
    const float4 v = *(const float4*)(src + base);
    ushort4 o;
    o.x = f2bf(v.x); o.y = f2bf(v.y); o.z = f2bf(v.z); o.w = f2bf(v.w);
    *(ushort4*)(dst + base) = o;
  } else if (b < 10240) {  // transpose Wv
    const int tb = b - 9216;
    const int bi = (tb & 31) * 32;   // output row block (i)
    const int bj = (tb >> 5) * 32;   // output col block (j) = src row block
    const int tx = tid & 31;
    const int ty = tid >> 5;  // 0..7
    for (int r = ty; r < 32; r += 8)
      tile[r][tx] = Wv[(long)(bj + r) * 1024 + bi + tx];
    __syncthreads();
    for (int r = ty; r < 32; r += 8)
      wvtb[(long)(bi + r) * 1024 + bj + tx] = f2bf(tile[tx][r]);
  } else {  // bias fold
    const int row = (b - 10240) * 4 + (tid >> 6);
    const int lane = tid & 63;
    const float* w = Wp + (long)row * 1024;
    float s = 0.f;
    for (int j = lane; j < 1024; j += 64) s += w[j] * bv[j];
    for (int off = 32; off; off >>= 1) s += __shfl_down(s, off, 64);
    if (lane == 0) cv[row] = 2048.f * s + bp[row];
  }
}

// ---------------------------------------------------------------------
// gemm0 (8-phase anatomy): Out[8192,1024] f32 = xb @ M2^T + cv
// BM=256 BN=128 BK=64, 512 thr = 8 waves (2Mx4N), wave tile 128x32,
// acc 8x2. 3 LDS buffers, depth-2 prefetch, counted vmcnt(6)/K-tile.
// LDS rows = 64 u16 (8 chunks x 16B); slot c of row r holds logical
// chunk c ^ (r&7); inverse perm on the glds source address.
__global__ __launch_bounds__(512) void k_gemm0(
    const u16* __restrict__ A, const u16* __restrict__ B, float* __restrict__ Out,
    const float* __restrict__ bias) {
  __shared__ u16 As[3][256 * 64];  // 3 x 32 KB
  __shared__ u16 Bs[3][128 * 64];  // 3 x 16 KB  (total 144 KB)

  const int tid = threadIdx.x;
  const int lane = tid & 63;
  const int wv = tid >> 6;           // 0..7
  const int waveM = (wv & 1) * 128;  // 2 waves in M
  const int waveN = (wv >> 1) * 32;  // 4 waves in N
  const int l15 = lane & 15;
  const int quad = lane >> 4;

  // XCD grouping over 256 blocks: xcd = id&7 owns m-panels
  // [xcd*4, +4); each panel's 8 n-blocks temporally adjacent (B-panel
  // 256 KB x 8 = 2 MB L2-fits).
  const int id = blockIdx.x;
  const int xcd = id & 7;
  const int j = id >> 3;                     // 0..31
  const long bm = (long)(xcd * 4 + (j >> 3)) * 256;
  const long bn = (long)(j & 7) * 128;

  // Staging: thread t -> row_local = t>>3 (0..63), LDS slot = t&7,
  // global chunk = (t&7) ^ (row&7). Call r covers rows [r*64, +64).
  const int rl = tid >> 3;
  const int cs = (tid & 7) ^ (rl & 7);
  const u16* Ag = A + (bm + rl) * 1024L + cs * 8;
  const u16* Bg = B + (bn + rl) * 1024L + cs * 8;

  // per K-tile: 4 A-calls + 2 B-calls = 6 glds/thread
  auto STAGE_A = [&](int tt, int r) {
    u16* d = &As[tt % 3][0] + r * 4096 + tid * 8;
    load16(Ag + ((long)tt << 6) + (long)r * 64 * 1024, d);
  };
  auto STAGE_B = [&](int tt, int r) {
    u16* d = &Bs[tt % 3][0] + r * 4096 + tid * 8;
    load16(Bg + ((long)tt << 6) + (long)r * 64 * 1024, d);
  };

  const f32x4 zero = {0.f, 0.f, 0.f, 0.f};
  f32x4 acc[8][2];
#pragma unroll
  for (int i = 0; i < 8; ++i)
#pragma unroll
    for (int jj = 0; jj < 2; ++jj) acc[i][jj] = zero;

  // Fragment read slots: logical chunk kk*4+quad of row (..+l15) sits
  // at slot ^ (l15&7)  (base rows are multiples of 8).
  const int rq0 = quad ^ (l15 & 7);        // kk = 0
  const int rq1 = (4 + quad) ^ (l15 & 7);  // kk = 1

  constexpr int nT = 16;  // K/BK

  // ---- prologue: stage tiles 0,1; wait tile 0 (tile 1 in flight) ----
#pragma unroll
  for (int r = 0; r < 4; ++r) STAGE_A(0, r);
  STAGE_B(0, 0); STAGE_B(0, 1);
#pragma unroll
  for (int r = 0; r < 4; ++r) STAGE_A(1, r);
  STAGE_B(1, 0); STAGE_B(1, 1);
  asm volatile("s_waitcnt vmcnt(6)" ::: "memory");
  __builtin_amdgcn_s_barrier();

  for (int t = 0; t < nT; ++t) {
    const u16* Asb = &As[t % 3][0];
    const u16* Bsb = &Bs[t % 3][0];
    const bool st = (t + 2) < nT;

    // ================= phase 0 (M-half 0) =================
    {
      bf16x8 af[2][4], bg[2][2];
#pragma unroll
      for (int i = 0; i < 4; ++i) {
        const int ra = (waveM + i * 16 + l15) * 64;
        af[0][i] = *(const bf16x8*)(Asb + ra + rq0 * 8);
        af[1][i] = *(const bf16x8*)(Asb + ra + rq1 * 8);
      }
#pragma unroll
      for (int jj = 0; jj < 2; ++jj) {
        const int rb = (waveN + jj * 16 + l15) * 64;
        bg[0][jj] = *(const bf16x8*)(Bsb + rb + rq0 * 8);
        bg[1][jj] = *(const bf16x8*)(Bsb + rb + rq1 * 8);
      }
      if (st) { STAGE_A(t + 2, 0); STAGE_A(t + 2, 1); STAGE_A(t + 2, 2); }
      __builtin_amdgcn_sched_barrier(0);   // pin stage issue before barrier
      __builtin_amdgcn_s_barrier();
      asm volatile("s_waitcnt lgkmcnt(0)" ::: "memory");
      __builtin_amdgcn_sched_barrier(0);   // rule #18
      __builtin_amdgcn_s_setprio(1);
#pragma unroll
      for (int kk = 0; kk < 2; ++kk)
#pragma unroll
        for (int i = 0; i < 4; ++i)
#pragma unroll
          for (int jj = 0; jj < 2; ++jj)
            acc[i][jj] = __builtin_amdgcn_mfma_f32_16x16x32_bf16(
                af[kk][i], bg[kk][jj], acc[i][jj], 0, 0, 0);
      __builtin_amdgcn_s_setprio(0);
      __builtin_amdgcn_s_barrier();
    }

    // ================= phase 1 (M-half 1) =================
    {
      bf16x8 af[2][4], bg[2][2];
#pragma unroll
      for (int i = 0; i < 4; ++i) {
        const int ra = (waveM + 64 + i * 16 + l15) * 64;
        af[0][i] = *(const bf16x8*)(Asb + ra + rq0 * 8);
        af[1][i] = *(const bf16x8*)(Asb + ra + rq1 * 8);
      }
#pragma unroll
      for (int jj = 0; jj < 2; ++jj) {
        const int rb = (waveN + jj * 16 + l15) * 64;
        bg[0][jj] = *(const bf16x8*)(Bsb + rb + rq0 * 8);
        bg[1][jj] = *(const bf16x8*)(Bsb + rb + rq1 * 8);
      }
      if (st) { STAGE_A(t + 2, 3); STAGE_B(t + 2, 0); STAGE_B(t + 2, 1); }
      __builtin_amdgcn_sched_barrier(0);
      __builtin_amdgcn_s_barrier();
      asm volatile("s_waitcnt lgkmcnt(0)" ::: "memory");
      __builtin_amdgcn_sched_barrier(0);
      __builtin_amdgcn_s_setprio(1);
#pragma unroll
      for (int kk = 0; kk < 2; ++kk)
#pragma unroll
        for (int i = 0; i < 4; ++i)
#pragma unroll
          for (int jj = 0; jj < 2; ++jj)
            acc[4 + i][jj] = __builtin_amdgcn_mfma_f32_16x16x32_bf16(
                af[kk][i], bg[kk][jj], acc[4 + i][jj], 0, 0, 0);
      __builtin_amdgcn_s_setprio(0);
      // counted wait, once per K-tile: tile t+1's 6 loads done;
      // tile t+2's 6 stay in flight across the barrier.
      if (st)                asm volatile("s_waitcnt vmcnt(6)" ::: "memory");
      else if (t + 1 < nT)   asm volatile("s_waitcnt vmcnt(0)" ::: "memory");
      __builtin_amdgcn_s_barrier();
    }
  }

  // epilogue: C/D layout col = lane&15, row = quad*4 + reg  [m89/m91]
#pragma unroll
  for (int i = 0; i < 8; ++i) {
    const long gm = bm + waveM + i * 16 + quad * 4;
#pragma unroll
    for (int jj = 0; jj < 2; ++jj) {
      const long gn = bn + waveN + jj * 16 + l15;
      const float bb = bias[gn];
#pragma unroll
      for (int r = 0; r < 4; ++r)
        Out[(gm + r) * 1024 + gn] = acc[i][jj][r] + bb;
    }
  }
}

// ---------------------------------------------------------------------
// gemm1 (R12 MODE1 verbatim): M2 = bf16(2048 * Wp @ Wv^T-input)
// 64x64 tile, BK=64, 256 thr = 4 waves (2x2, wave 32x32, acc 2x2),
// glds both operands, drain-after-MFMA, 256-block grid, 32 KB LDS.
__global__ __launch_bounds__(256) void k_gemm1(
    const u16* __restrict__ A, const u16* __restrict__ B, u16* __restrict__ Out,
    int M, int N, int K) {
  __shared__ u16 As[2][64 * 64];  // 2 x 8 KB
  __shared__ u16 Bs[2][64 * 64];  // 2 x 8 KB

  const int tid = threadIdx.x;
  const int lane = tid & 63;
  const int wv = tid >> 6;
  const int waveM = (wv & 1) << 5;
  const int waveN = (wv >> 1) << 5;
  const int l15 = lane & 15;
  const int quad = lane >> 4;

  const long bm = (long)(blockIdx.x >> 4) * 64;
  const long bn = (long)(blockIdx.x & 15) * 64;

  const int rl = tid >> 3;
  const int cs = (tid & 7) ^ (rl & 7);
  const u16* Ag0 = A + (bm + rl) * (long)K + cs * 8;
  const u16* Bg0 = B + (bn + rl) * (long)K + cs * 8;
  constexpr int RPC = 32;  // rows per glds call

  const int nT = K >> 6;  // 16 K-tiles

  auto STAGE = [&](long k0, int b) {
    u16* Ad = &As[b][0] + tid * 8;
    u16* Bd = &Bs[b][0] + tid * 8;
    load16(Ag0 + k0, Ad);
    load16(Ag0 + k0 + (long)RPC * K, Ad + RPC * 64);
    load16(Bg0 + k0, Bd);
    load16(Bg0 + k0 + (long)RPC * K, Bd + RPC * 64);
  };

  const f32x4 zero = {0.f, 0.f, 0.f, 0.f};
  f32x4 acc[2][2];
#pragma unroll
  for (int i = 0; i < 2; ++i)
#pragma unroll
    for (int j = 0; j < 2; ++j) acc[i][j] = zero;

  const int rq0 = quad ^ (l15 & 7);        // kk = 0
  const int rq1 = (4 + quad) ^ (l15 & 7);  // kk = 1

  STAGE(0, 0);
  asm volatile("s_waitcnt vmcnt(0)" ::: "memory");
  __builtin_amdgcn_s_barrier();

  int cur = 0;
  for (int t = 0; t < nT; ++t) {
    const bool more = (t + 1) < nT;
    if (more) STAGE((long)(t + 1) << 6, cur ^ 1);
    __builtin_amdgcn_sched_barrier(0);

    const u16* Asb = &As[cur][0];
    const u16* Bsb = &Bs[cur][0];
    bf16x8 af[2][2], bg[2][2];
#pragma unroll
    for (int i = 0; i < 2; ++i) {
      const int ra = (waveM + i * 16 + l15) * 64;
      af[0][i] = *(const bf16x8*)(Asb + ra + rq0 * 8);
      af[1][i] = *(const bf16x8*)(Asb + ra + rq1 * 8);
    }
#pragma unroll
    for (int j = 0; j < 2; ++j) {
      const int rb = (waveN + j * 16 + l15) * 64;
      bg[0][j] = *(const bf16x8*)(Bsb + rb + rq0 * 8);
      bg[1][j] = *(const bf16x8*)(Bsb + rb + rq1 * 8);
    }
    asm volatile("s_waitcnt lgkmcnt(0)" ::: "memory");
    __builtin_amdgcn_sched_barrier(0);

#pragma unroll
    for (int kk = 0; kk < 2; ++kk)
#pragma unroll
      for (int i = 0; i < 2; ++i)
#pragma unroll
        for (int j = 0; j < 2; ++j)
          acc[i][j] = __builtin_amdgcn_mfma_f32_16x16x32_bf16(af[kk][i], bg[kk][j],
                                                              acc[i][j], 0, 0, 0);

    if (more) {
      asm volatile("s_waitcnt vmcnt(0)" ::: "memory");
      __builtin_amdgcn_s_barrier();
      cur ^= 1;
    }
  }

#pragma unroll
  for (int i = 0; i < 2; ++i) {
    const long gm = bm + waveM + i * 16 + quad * 4;
#pragma unroll
    for (int j = 0; j < 2; ++j) {
      const long gn = bn + waveN + j * 16 + l15;
#pragma unroll
      for (int r = 0; r < 4; ++r)
        Out[(gm + r) * N + gn] = f2bf(acc[i][j][r] * 2048.f);
    }
  }
}

// =====================================================================
extern "C" void kernel_launch(void* const* d_in, const int* in_sizes, int n_in,
                              void* d_out, int out_size, void* d_ws, size_t ws_size,
                              hipStream_t stream) {
  // setup_inputs order: x, Wq, bq, Wk, bk, Wv, bv, Wp, bp
  const float* x  = (const float*)d_in[0];
  const float* Wv = (const float*)d_in[5];
  const float* bv = (const float*)d_in[6];
  const float* Wp = (const float*)d_in[7];
  const float* bp = (const float*)d_in[8];

  char* ws = (char*)d_ws;
  u16* xb    = (u16*)(ws);                      // 16 MB  x bf16
  u16* wpb   = (u16*)(ws + (16u << 20));        //  2 MB  Wp bf16
  u16* wvtb  = (u16*)(ws + (18u << 20));        //  2 MB  Wv^T bf16
  u16* m2b   = (u16*)(ws + (20u << 20));        //  2 MB  M2 bf16
  float* cv  = (float*)(ws + (22u << 20));      //  4 KB  folded bias

  // 1) fused prep: conv x / conv Wp / transpose Wv / bias fold
  k_prep<<<10496, 256, 0, stream>>>(x, Wv, bv, Wp, bp, xb, wpb, wvtb, cv);

  // 2) M2 = bf16(2048 * Wp @ Wv)  (64^2 tiles: 256 blocks, 16 iters)
  k_gemm1<<<256, 256, 0, stream>>>(wpb, wvtb, m2b, 1024, 1024, 1024);

  // 3) out = xb @ M2^T + cv  (256x128 tiles: 256 blocks, 8-phase)
  k_gemm0<<<256, 512, 0, stream>>>(xb, m2b, (float*)d_out, cv);
}

// Round 10
// 136.386 us; speedup vs baseline: 1.1003x; 1.0514x over previous
//
#include <hip/hip_runtime.h>
#include <cstdint>

// =====================================================================
// MultiHeadAttention_84576495993495  (round 17 -- FINAL: reversion to
// the verified-best round-12 kernel)
//
// Algebraic collapse: einsum('bhqk,bhvo->bhvo', attn, v) sums attn over
// BOTH q and k; softmax rows sum to 1 -> factor is exactly S=2048.
//   final = x @ (2048*Wp@Wv)^T + (2048*Wp@bv + bp)
// Wq/bq/Wk/bk unused.
//
// Session record (dur_us): R7 143.0 | R8 153.7 | R9 145.4 | R10 140.5
// | R11 144.8 | R12 139.1* | R13 150.1 | R14 148.7 | R15 147.9 |
// R16 143.4.  Every verified technique class (2-phase drain, counted
// vmcnt depth-2/3, waves/block, fused-A reg-staging, blocks/CU
// residency, 8-phase+setprio) lands in a 139-154us band.
//
// Floor model (counters): 2 x ~42us 256MB harness fills @80% HBM in
// every rocprof top-5 (~84us fixed) + prep ~9us + gemm1 ~7us + gemm0
// ~30-38us + launch gaps ~5us = ~135-140us. R12 sits on it. The
// remaining GEMM inefficiency is the only compressible term and six
// structurally distinct attacks were null within noise -> reverting
// to R12 verbatim; if it reproduces, the measured floor is declared.
// =====================================================================

typedef unsigned short u16;
typedef __bf16 bf16x8 __attribute__((ext_vector_type(8)));
typedef float f32x4 __attribute__((ext_vector_type(4)));

__device__ __forceinline__ u16 f2bf(float f) {
  // round-to-nearest-even f32 -> bf16 bits (finite inputs)
  unsigned int u = __float_as_uint(f);
  u += 0x7fffu + ((u >> 16) & 1u);
  return (u16)(u >> 16);
}

// async global->LDS 16B copy; LDS dest = wave-uniform base + lane*16
__device__ __forceinline__ void load16(const void* g, void* l) {
  auto gp = (const __attribute__((address_space(1))) unsigned int*)(uintptr_t)g;
  auto lp = (__attribute__((address_space(3))) unsigned int*)(unsigned int)(uintptr_t)l;
  __builtin_amdgcn_global_load_lds(gp, lp, 16, 0, 0);
}

// ---------------------------------------------------------------------
// Fused prep. Block ranges:
//   [0,8192)      conv x   f32->bf16 (4 elem/thread)
//   [8192,9216)   conv Wp  f32->bf16
//   [9216,10240)  transpose+conv Wv -> Wv^T bf16 (32x32 tiles)
//   [10240,10496) cv[n] = 2048*dot(Wp[n,:],bv) + bp[n]
__global__ void k_prep(const float* __restrict__ x, const float* __restrict__ Wv,
                       const float* __restrict__ bv, const float* __restrict__ Wp,
                       const float* __restrict__ bp, u16* __restrict__ xb,
                       u16* __restrict__ wpb, u16* __restrict__ wvtb,
                       float* __restrict__ cv) {
  __shared__ float tile[32][33];
  const int b = blockIdx.x;
  const int tid = threadIdx.x;
  if (b < 9216) {  // conversions
    const float* src = (b < 8192) ? x : Wp;
    u16* dst = (b < 8192) ? xb : wpb;
    const long base = (long)((b < 8192) ? b : (b - 8192)) * 1024 + tid * 4;
    const float4 v = *(const float4*)(src + base);
    ushort4 o;
    o.x = f2bf(v.x); o.y = f2bf(v.y); o.z = f2bf(v.z); o.w = f2bf(v.w);
    *(ushort4*)(dst + base) = o;
  } else if (b < 10240) {  // transpose Wv
    const int tb = b - 9216;
    const int bi = (tb & 31) * 32;   // output row block (i)
    const int bj = (tb >> 5) * 32;   // output col block (j) = src row block
    const int tx = tid & 31;
    const int ty = tid >> 5;  // 0..7
    for (int r = ty; r < 32; r += 8)
      tile[r][tx] = Wv[(long)(bj + r) * 1024 + bi + tx];
    __syncthreads();
    for (int r = ty; r < 32; r += 8)
      wvtb[(long)(bi + r) * 1024 + bj + tx] = f2bf(tile[tx][r]);
  } else {  // bias fold
    const int row = (b - 10240) * 4 + (tid >> 6);
    const int lane = tid & 63;
    const float* w = Wp + (long)row * 1024;
    float s = 0.f;
    for (int j = lane; j < 1024; j += 64) s += w[j] * bv[j];
    for (int off = 32; off; off >>= 1) s += __shfl_down(s, off, 64);
    if (lane == 0) cv[row] = 2048.f * s + bp[row];
  }
}

// ---------------------------------------------------------------------
// NT bf16 GEMM: Out[M,N] = A[M,K] @ B[N,K]^T  (+bias or *2048->bf16)
// R10 schedule (verified best): 2-phase dbuf, per iter
//   STAGE(t+1) -> ds_read(t) -> lgkmcnt(0) -> MFMA -> vmcnt(0) -> bar.
// LDS: 64 u16/row, slot c of row r holds global chunk c ^ (r&7);
// fragment ds_read_b128 aliases 2-way (free, m136).
// MODE 0: BM=BN=128, 512 thr = 8 waves (2Mx4N, tile 64x32, acc 4x2),
//         f32 out + bias, XCD-grouped 512-block grid, 64 KB LDS.
// MODE 1: BM=BN=64, 256 thr = 4 waves (2x2, tile 32x32, acc 2x2),
//         bf16 out * 2048, 256-block grid (1/CU), 32 KB LDS.
template <int MODE>
__global__ __launch_bounds__(MODE == 0 ? 512 : 256) void k_gemm(
    const u16* __restrict__ A, const u16* __restrict__ B, void* __restrict__ OutV,
    const float* __restrict__ bias, int M, int N, int K) {
  constexpr int BM = (MODE == 0) ? 128 : 64;
  constexpr int BN = (MODE == 0) ? 128 : 64;
  constexpr int T  = (MODE == 0) ? 512 : 256;
  constexpr int WTM = (MODE == 0) ? 64 : 32;  // wave tile M
  constexpr int WTN = 32;                      // wave tile N
  constexpr int AccM = WTM / 16;               // 4 or 2
  constexpr int AccN = WTN / 16;               // 2
  constexpr int RPC = T / 8;                   // staged rows per call

  __shared__ u16 As[2][BM * 64];
  __shared__ u16 Bs[2][BN * 64];

  const int tid = threadIdx.x;
  const int lane = tid & 63;
  const int wv = tid >> 6;
  const int waveM = (wv & 1) * WTM;
  const int waveN = (wv >> 1) * WTN;
  const int l15 = lane & 15;
  const int quad = lane >> 4;

  long bm, bn;
  if constexpr (MODE == 0) {
    // XCD grouping: xcd = id&7 owns 8 contiguous m-panels; a panel's 8
    // n-blocks are temporally adjacent on that XCD (B = 2 MB L2-fits).
    const int id = blockIdx.x;            // gridDim.x = (M/128)*(N/128)
    const int xcd = id & 7;
    const int j = id >> 3;
    const int nb = N >> 7;
    const int mPerXcd = M / 128 / 8;
    bm = (long)(xcd * mPerXcd + j / nb) * 128;
    bn = (long)(j % nb) * 128;
  } else {
    // 256 blocks (16x16 of 64^2 tiles) -- full GPU; Wp/Wv panels all
    // L2-fit so no special locality mapping needed.
    bm = (long)(blockIdx.x >> 4) * 64;
    bn = (long)(blockIdx.x & 15) * 64;
  }

  // Staging: 2 calls each for A and B per tile; call r covers rows
  // [r*RPC, +RPC), dest = linear LDS base + tid*16B (wave-uniform base
  // + lane*16 per wave). Thread t: row = t>>3, LDS slot = t&7, global
  // chunk cs = (t&7) ^ (row&7)  [RPC multiple of 8 keeps row&7 = t>>3&7].
  const int rl = tid >> 3;
  const int cs = (tid & 7) ^ (rl & 7);
  const u16* Ag0 = A + (bm + rl) * (long)K + cs * 8;
  const u16* Bg0 = B + (bn + rl) * (long)K + cs * 8;

  const int nT = K >> 6;  // # K-tiles (16 for K=1024)

  // stage tile at k-offset k0 (elems) into buffer b (4 load16/thread)
  auto STAGE = [&](long k0, int b) {
    u16* Ad = &As[b][0] + tid * 8;
    u16* Bd = &Bs[b][0] + tid * 8;
    load16(Ag0 + k0, Ad);
    load16(Ag0 + k0 + (long)RPC * K, Ad + RPC * 64);
    load16(Bg0 + k0, Bd);
    load16(Bg0 + k0 + (long)RPC * K, Bd + RPC * 64);
  };

  const f32x4 zero = {0.f, 0.f, 0.f, 0.f};
  f32x4 acc[AccM][AccN];
#pragma unroll
  for (int i = 0; i < AccM; ++i)
#pragma unroll
    for (int j = 0; j < AccN; ++j) acc[i][j] = zero;

  // Fragment read slots (swizzled): logical chunk kk*4+quad of row
  // (..+l15) sits at slot ^ (l15&7)  (base rows are multiples of 8).
  const int rq0 = quad ^ (l15 & 7);        // kk = 0
  const int rq1 = (4 + quad) ^ (l15 & 7);  // kk = 1

  // ---- prologue: stage tile 0, drain once, barrier ----
  STAGE(0, 0);
  asm volatile("s_waitcnt vmcnt(0)" ::: "memory");
  __builtin_amdgcn_s_barrier();

  int cur = 0;
  for (int t = 0; t < nT; ++t) {
    const bool more = (t + 1) < nT;
    if (more) STAGE((long)(t + 1) << 6, cur ^ 1);
    __builtin_amdgcn_sched_barrier(0);  // keep stage issue ahead of reads

    const u16* Asb = &As[cur][0];
    const u16* Bsb = &Bs[cur][0];
    bf16x8 af[2][AccM], bg[2][AccN];
#pragma unroll
    for (int i = 0; i < AccM; ++i) {
      const int ra = (waveM + i * 16 + l15) * 64;
      af[0][i] = *(const bf16x8*)(Asb + ra + rq0 * 8);
      af[1][i] = *(const bf16x8*)(Asb + ra + rq1 * 8);
    }
#pragma unroll
    for (int j = 0; j < AccN; ++j) {
      const int rb = (waveN + j * 16 + l15) * 64;
      bg[0][j] = *(const bf16x8*)(Bsb + rb + rq0 * 8);
      bg[1][j] = *(const bf16x8*)(Bsb + rb + rq1 * 8);
    }
    asm volatile("s_waitcnt lgkmcnt(0)" ::: "memory");
    __builtin_amdgcn_sched_barrier(0);  // rule #18: no MFMA hoist past wait

#pragma unroll
    for (int kk = 0; kk < 2; ++kk)
#pragma unroll
      for (int i = 0; i < AccM; ++i)
#pragma unroll
        for (int j = 0; j < AccN; ++j)
          acc[i][j] = __builtin_amdgcn_mfma_f32_16x16x32_bf16(af[kk][i], bg[kk][j],
                                                              acc[i][j], 0, 0, 0);

    if (more) {
      // next tile's 8 loads had the whole read+MFMA phase to land
      asm volatile("s_waitcnt vmcnt(0)" ::: "memory");
      __builtin_amdgcn_s_barrier();
      cur ^= 1;
    }
  }

  // epilogue: C/D layout col = lane&15, row = quad*4 + reg  [m89/m91]
#pragma unroll
  for (int i = 0; i < AccM; ++i) {
    const long gm = bm + waveM + i * 16 + quad * 4;
#pragma unroll
    for (int j = 0; j < AccN; ++j) {
      const long gn = bn + waveN + j * 16 + l15;
      if constexpr (MODE == 0) {
        float* outp = (float*)OutV;
        const float bb = bias[gn];
#pragma unroll
        for (int r = 0; r < 4; ++r)
          outp[(gm + r) * N + gn] = acc[i][j][r] + bb;
      } else {
        u16* outp = (u16*)OutV;
#pragma unroll
        for (int r = 0; r < 4; ++r)
          outp[(gm + r) * N + gn] = f2bf(acc[i][j][r] * 2048.f);
      }
    }
  }
}

// =====================================================================
extern "C" void kernel_launch(void* const* d_in, const int* in_sizes, int n_in,
                              void* d_out, int out_size, void* d_ws, size_t ws_size,
                              hipStream_t stream) {
  // setup_inputs order: x, Wq, bq, Wk, bk, Wv, bv, Wp, bp
  const float* x  = (const float*)d_in[0];
  const float* Wv = (const float*)d_in[5];
  const float* bv = (const float*)d_in[6];
  const float* Wp = (const float*)d_in[7];
  const float* bp = (const float*)d_in[8];

  char* ws = (char*)d_ws;
  u16* xb    = (u16*)(ws);                      // 16 MB  x bf16
  u16* wpb   = (u16*)(ws + (16u << 20));        //  2 MB  Wp bf16
  u16* wvtb  = (u16*)(ws + (18u << 20));        //  2 MB  Wv^T bf16
  u16* m2b   = (u16*)(ws + (20u << 20));        //  2 MB  M2 bf16
  float* cv  = (float*)(ws + (22u << 20));      //  4 KB  folded bias

  // 1) fused prep: conv x / conv Wp / transpose Wv / bias fold
  k_prep<<<10496, 256, 0, stream>>>(x, Wv, bv, Wp, bp, xb, wpb, wvtb, cv);

  // 2) M2 = bf16(2048 * Wp @ Wv)  (64^2 tiles: 256 blocks, 16 iters)
  k_gemm<1><<<256, 256, 0, stream>>>(wpb, wvtb, m2b, nullptr, 1024, 1024, 1024);

  // 3) out = x @ M2^T + cv  (64 panels x 8 n-blocks = 512, XCD-grouped)
  k_gemm<0><<<512, 512, 0, stream>>>(xb, m2b, d_out, cv, 8192, 1024, 1024);
}